// Round 4
// baseline (279.319 us; speedup 1.0000x reference)
//
#include <hip/hip_runtime.h>
#include <stdint.h>

#define N 8192
#define DIM 1024
#define EPSF 1e-8f
#define NBLK 32           // 8192/256
#define NTRI 528          // NBLK*(NBLK+1)/2

typedef __attribute__((ext_vector_type(4))) float f32x4;
typedef __attribute__((ext_vector_type(8))) short s16x8;

// ---- helpers ----
__device__ inline unsigned short f2bf(float f) {
  unsigned u = __float_as_uint(f);
  unsigned r = (u + 0x7FFFu + ((u >> 16) & 1u)) >> 16;
  return (unsigned short)r;
}

__device__ inline unsigned encf(float f) {
  unsigned u = __float_as_uint(f);
  return (u & 0x80000000u) ? ~u : (u | 0x80000000u);
}

// ws layout:
//   [0, 16MiB)       : xb   bf16 normalized rows, row-major 8192x1024 (ushort)
//   [16777216,+32KiB): invn fp32 per-row 1/max(norm,eps)
//   [16809984,+64KiB): keys u64 packed (enc(sim)<<32)|~col
//   [16875520,+32KiB): part fp32 per-row log(dist+eps)
#define XB_OFF   0
#define INV_OFF  16777216
#define KEY_OFF  16809984
#define PART_OFF 16875520

// ---------------- kernel 1: normalize + init ----------------
__global__ __launch_bounds__(256)
void k_norm(const float* __restrict__ x, unsigned short* __restrict__ xb,
            float* __restrict__ invn, unsigned long long* __restrict__ keys) {
  int row = blockIdx.x, t = threadIdx.x;
  const float4* xr = (const float4*)(x + (size_t)row * DIM);
  float4 v = xr[t];
  float ss = v.x * v.x + v.y * v.y + v.z * v.z + v.w * v.w;
#pragma unroll
  for (int o = 32; o > 0; o >>= 1) ss += __shfl_down(ss, o, 64);
  __shared__ float red[4];
  __shared__ float sinv;
  if ((t & 63) == 0) red[t >> 6] = ss;
  __syncthreads();
  if (t == 0) {
    float s = red[0] + red[1] + red[2] + red[3];
    float inv = 1.0f / fmaxf(sqrtf(s), EPSF);
    sinv = inv;
    invn[row] = inv;
    keys[row] = 0ull;           // any sim >= -1 encodes > 0
  }
  __syncthreads();
  float inv = sinv;
  ushort4 o4;
  o4.x = f2bf(v.x * inv);
  o4.y = f2bf(v.y * inv);
  o4.z = f2bf(v.z * inv);
  o4.w = f2bf(v.w * inv);
  ((ushort4*)(xb + (size_t)row * DIM))[t] = o4;
}

// ---------------- kernel 2: sim GEMM + argmax (256^2 tile, pipelined) ----------------
// 512 threads = 8 waves (2Mx4N), per-wave 128x64 output, BK=32, 2 LDS buffers.
// Phase structure per K-tile: {stage next-A; read A-half + all B; bar; MFMA*16; bar;
//                              stage next-B; read A-half; bar; MFMA*16; vmcnt(0); bar}
// Raw s_barrier + asm vmcnt keeps prefetch loads in flight across barriers
// (no __syncthreads: it would drain vmcnt every phase).
__global__ __launch_bounds__(512, 2)
void k_sim(const unsigned short* __restrict__ xb, unsigned long long* __restrict__ keys) {
  int b = blockIdx.x;
  int bi = (int)((65.0f - sqrtf(4225.0f - 8.0f * (float)b)) * 0.5f);
  while ((bi + 1) * (65 - (bi + 1)) / 2 <= b) ++bi;
  while (bi * (65 - bi) / 2 > b) --bi;
  int bj = bi + (b - bi * (65 - bi) / 2);

  __shared__ unsigned short sA[2][8192];   // [buf][256 rows x 32 cols]
  __shared__ unsigned short sB[2][8192];

  const int t = threadIdx.x, lane = t & 63, wv = t >> 6;
  const int wr = wv >> 2, wc = wv & 3;       // wave -> (2M x 4N) grid
  const int hi = lane >> 4, lo = lane & 15;
  const int rowBase = bi * 256, colBase = bj * 256;

  const unsigned short* gA = xb + (size_t)rowBase * DIM;
  const unsigned short* gB = xb + (size_t)colBase * DIM;

  // staging per-lane constants: linear chunk ci = p*512 + wv*64 + lane,
  // row r = ci>>2, slot s = ci&3, source chunk g = s ^ ((r>>1)&3)  (swizzle)
  const int sg = (lane & 3) ^ ((lane >> 3) & 3);
  const int r0 = wv * 16 + (lane >> 2);
  const size_t so0 = (size_t)r0 * DIM + sg * 8;           // p=0, rows 0..127
  const size_t so1 = (size_t)(r0 + 128) * DIM + sg * 8;   // p=1, rows 128..255
  const int lb0 = wv * 512;                               // LDS ushort base, p=0
  const int lb1 = 4096 + wv * 512;                        // p=1

  const f32x4 fzero = {0.f, 0.f, 0.f, 0.f};
  f32x4 acc[8][4];
#pragma unroll
  for (int i = 0; i < 8; ++i)
#pragma unroll
    for (int j = 0; j < 4; ++j) acc[i][j] = fzero;

  // fragment-read swizzled chunk (row low bits come only from lo)
  const int sr8 = (hi ^ ((lo >> 1) & 3)) * 8;

  // ---- prologue: stage kt=0 into buf 0 ----
  __builtin_amdgcn_global_load_lds((const __attribute__((address_space(1))) void*)(gA + so0),
                                   (__attribute__((address_space(3))) void*)(&sA[0][lb0]), 16, 0, 0);
  __builtin_amdgcn_global_load_lds((const __attribute__((address_space(1))) void*)(gA + so1),
                                   (__attribute__((address_space(3))) void*)(&sA[0][lb1]), 16, 0, 0);
  __builtin_amdgcn_global_load_lds((const __attribute__((address_space(1))) void*)(gB + so0),
                                   (__attribute__((address_space(3))) void*)(&sB[0][lb0]), 16, 0, 0);
  __builtin_amdgcn_global_load_lds((const __attribute__((address_space(1))) void*)(gB + so1),
                                   (__attribute__((address_space(3))) void*)(&sB[0][lb1]), 16, 0, 0);
  asm volatile("s_waitcnt vmcnt(0)" ::: "memory");
  __builtin_amdgcn_s_barrier();

  for (int kt = 0; kt < 32; ++kt) {
    const int cur = kt & 1, nxt = cur ^ 1;
    const size_t ko = (size_t)(kt + 1) * 32;
    s16x8 af[4], bf[4];

    // ======== phase a: quad mh=0 x all ni ========
    if (kt < 31) {  // stage A(kt+1) -> other buffer (its last reads retired before prev final barrier)
      __builtin_amdgcn_global_load_lds((const __attribute__((address_space(1))) void*)(gA + so0 + ko),
                                       (__attribute__((address_space(3))) void*)(&sA[nxt][lb0]), 16, 0, 0);
      __builtin_amdgcn_global_load_lds((const __attribute__((address_space(1))) void*)(gA + so1 + ko),
                                       (__attribute__((address_space(3))) void*)(&sA[nxt][lb1]), 16, 0, 0);
    }
#pragma unroll
    for (int mi = 0; mi < 4; ++mi) {
      int r = wr * 128 + mi * 16 + lo;
      af[mi] = *(const s16x8*)(&sA[cur][r * 32 + sr8]);
    }
#pragma unroll
    for (int ni = 0; ni < 4; ++ni) {
      int r = wc * 64 + ni * 16 + lo;
      bf[ni] = *(const s16x8*)(&sB[cur][r * 32 + sr8]);
    }
    __builtin_amdgcn_s_barrier();
    __builtin_amdgcn_s_setprio(1);
#pragma unroll
    for (int mi = 0; mi < 4; ++mi)
#pragma unroll
      for (int ni = 0; ni < 4; ++ni)
        acc[mi][ni] = __builtin_amdgcn_mfma_f32_16x16x32_bf16(af[mi], bf[ni], acc[mi][ni], 0, 0, 0);
    __builtin_amdgcn_s_setprio(0);
    __builtin_amdgcn_s_barrier();

    // ======== phase b: quad mh=1 x all ni (reuse bf) ========
    if (kt < 31) {  // stage B(kt+1)
      __builtin_amdgcn_global_load_lds((const __attribute__((address_space(1))) void*)(gB + so0 + ko),
                                       (__attribute__((address_space(3))) void*)(&sB[nxt][lb0]), 16, 0, 0);
      __builtin_amdgcn_global_load_lds((const __attribute__((address_space(1))) void*)(gB + so1 + ko),
                                       (__attribute__((address_space(3))) void*)(&sB[nxt][lb1]), 16, 0, 0);
    }
#pragma unroll
    for (int mi = 0; mi < 4; ++mi) {
      int r = wr * 128 + 64 + mi * 16 + lo;
      af[mi] = *(const s16x8*)(&sA[cur][r * 32 + sr8]);
    }
    __builtin_amdgcn_s_barrier();
    __builtin_amdgcn_s_setprio(1);
#pragma unroll
    for (int mi = 0; mi < 4; ++mi)
#pragma unroll
      for (int ni = 0; ni < 4; ++ni)
        acc[4 + mi][ni] = __builtin_amdgcn_mfma_f32_16x16x32_bf16(af[mi], bf[ni], acc[4 + mi][ni], 0, 0, 0);
    __builtin_amdgcn_s_setprio(0);
    // drain: guarantees kt+1's 8 loads (all waves, via barrier) landed before next reads
    asm volatile("s_waitcnt vmcnt(0)" ::: "memory");
    __builtin_amdgcn_s_barrier();
  }

  // ---- per-row argmax (C layout: col=lane&15, row=(lane>>4)*4+reg) ----
#pragma unroll
  for (int am = 0; am < 8; ++am) {
#pragma unroll
    for (int reg = 0; reg < 4; ++reg) {
      int grow = rowBase + wr * 128 + am * 16 + hi * 4 + reg;
      float best = -10.0f;
      int bcol = 0;
#pragma unroll
      for (int ni = 0; ni < 4; ++ni) {
        int gcol = colBase + wc * 64 + ni * 16 + lo;
        float v = acc[am][ni][reg];
        v = (gcol == grow) ? -10.0f : v;   // mask diagonal
        if (v > best || (v == best && gcol < bcol)) { best = v; bcol = gcol; }
      }
#pragma unroll
      for (int m = 1; m < 16; m <<= 1) {
        float ov = __shfl_xor(best, m, 64);
        int oc = __shfl_xor(bcol, m, 64);
        if (ov > best || (ov == best && oc < bcol)) { best = ov; bcol = oc; }
      }
      if (lo == 0) {
        unsigned long long key = ((unsigned long long)encf(best) << 32) | (unsigned)(~bcol);
        atomicMax(&keys[grow], key);
      }
    }
  }

  // ---- per-col argmax (symmetric contribution), off-diagonal blocks only ----
  if (bi != bj) {
#pragma unroll
    for (int ni = 0; ni < 4; ++ni) {
      int gcol = colBase + wc * 64 + ni * 16 + lo;
      float best = -10.0f;
      int brow = 0;
#pragma unroll
      for (int am = 0; am < 8; ++am)
#pragma unroll
        for (int reg = 0; reg < 4; ++reg) {
          int grow = rowBase + wr * 128 + am * 16 + hi * 4 + reg;
          float v = acc[am][ni][reg];
          if (v > best || (v == best && grow < brow)) { best = v; brow = grow; }
        }
#pragma unroll
      for (int m = 16; m < 64; m <<= 1) {
        float ov = __shfl_xor(best, m, 64);
        int oc = __shfl_xor(brow, m, 64);
        if (ov > best || (ov == best && oc < brow)) { best = ov; brow = oc; }
      }
      if (hi == 0) {
        unsigned long long key = ((unsigned long long)encf(best) << 32) | (unsigned)(~brow);
        atomicMax(&keys[gcol], key);
      }
    }
  }
}

// ---------------- kernel 3: exact fp32 distance -> per-row partial ----------------
__global__ __launch_bounds__(256)
void k_dist(const float* __restrict__ x, const float* __restrict__ invn,
            const unsigned long long* __restrict__ keys, float* __restrict__ part) {
  int row = blockIdx.x, t = threadIdx.x;
  unsigned long long key = keys[row];
  int nb = (int)(~(unsigned)key);       // decode ~col
  float ia = invn[row], ib = invn[nb];
  float4 a = ((const float4*)(x + (size_t)row * DIM))[t];
  float4 b = ((const float4*)(x + (size_t)nb * DIM))[t];
  float d0 = a.x * ia - b.x * ib + EPSF;
  float d1 = a.y * ia - b.y * ib + EPSF;
  float d2 = a.z * ia - b.z * ib + EPSF;
  float d3 = a.w * ia - b.w * ib + EPSF;
  float ss = d0 * d0 + d1 * d1 + d2 * d2 + d3 * d3;
#pragma unroll
  for (int o = 32; o > 0; o >>= 1) ss += __shfl_down(ss, o, 64);
  __shared__ float red[4];
  if ((t & 63) == 0) red[t >> 6] = ss;
  __syncthreads();
  if (t == 0) {
    float s = red[0] + red[1] + red[2] + red[3];
    part[row] = logf(sqrtf(s) + EPSF);
  }
}

// ---------------- kernel 4: final reduce (no atomics) ----------------
__global__ __launch_bounds__(1024)
void k_final(const float* __restrict__ part, float* __restrict__ out) {
  int t = threadIdx.x;
  float s = 0.0f;
#pragma unroll
  for (int i = 0; i < N / 1024; ++i) s += part[t + i * 1024];
#pragma unroll
  for (int o = 32; o > 0; o >>= 1) s += __shfl_down(s, o, 64);
  __shared__ float red[16];
  if ((t & 63) == 0) red[t >> 6] = s;
  __syncthreads();
  if (t == 0) {
    float tot = 0.0f;
#pragma unroll
    for (int i = 0; i < 16; ++i) tot += red[i];
    out[0] = -tot / (float)N;
  }
}

extern "C" void kernel_launch(void* const* d_in, const int* in_sizes, int n_in,
                              void* d_out, int out_size, void* d_ws, size_t ws_size,
                              hipStream_t stream) {
  const float* x = (const float*)d_in[0];
  float* out = (float*)d_out;
  char* ws = (char*)d_ws;
  unsigned short* xb = (unsigned short*)(ws + XB_OFF);
  float* invn = (float*)(ws + INV_OFF);
  unsigned long long* keys = (unsigned long long*)(ws + KEY_OFF);
  float* part = (float*)(ws + PART_OFF);

  k_norm<<<N, 256, 0, stream>>>(x, xb, invn, keys);
  k_sim<<<NTRI, 512, 0, stream>>>(xb, keys);
  k_dist<<<N, 256, 0, stream>>>(x, invn, keys, part);
  k_final<<<1, 1024, 0, stream>>>(part, out);
}

// Round 5
// 239.888 us; speedup vs baseline: 1.1644x; 1.1644x over previous
//
#include <hip/hip_runtime.h>
#include <stdint.h>

#define N 8192
#define DIM 1024
#define EPSF 1e-8f
#define NBLK 32           // 8192/256
#define NTRI 528          // NBLK*(NBLK+1)/2
#define NKT 32            // K-tiles of 32: 1024/32

typedef __attribute__((ext_vector_type(4))) float f32x4;
typedef __attribute__((ext_vector_type(8))) short s16x8;

// ---- helpers ----
__device__ inline unsigned short f2bf(float f) {
  unsigned u = __float_as_uint(f);
  unsigned r = (u + 0x7FFFu + ((u >> 16) & 1u)) >> 16;
  return (unsigned short)r;
}

__device__ inline unsigned encf(float f) {
  unsigned u = __float_as_uint(f);
  return (u & 0x80000000u) ? ~u : (u | 0x80000000u);
}

// ws layout:
//   [0, 16MiB)       : xb   bf16 normalized rows, row-major 8192x1024 (ushort)
//   [16777216,+32KiB): invn fp32 per-row 1/max(norm,eps)
//   [16809984,+64KiB): keys u64 packed (enc(sim)<<32)|~col
//   [16875520,+32KiB): part fp32 per-row log(dist+eps)
#define XB_OFF   0
#define INV_OFF  16777216
#define KEY_OFF  16809984
#define PART_OFF 16875520

// ---------------- kernel 1: normalize + init ----------------
__global__ __launch_bounds__(256)
void k_norm(const float* __restrict__ x, unsigned short* __restrict__ xb,
            float* __restrict__ invn, unsigned long long* __restrict__ keys) {
  int row = blockIdx.x, t = threadIdx.x;
  const float4* xr = (const float4*)(x + (size_t)row * DIM);
  float4 v = xr[t];
  float ss = v.x * v.x + v.y * v.y + v.z * v.z + v.w * v.w;
#pragma unroll
  for (int o = 32; o > 0; o >>= 1) ss += __shfl_down(ss, o, 64);
  __shared__ float red[4];
  __shared__ float sinv;
  if ((t & 63) == 0) red[t >> 6] = ss;
  __syncthreads();
  if (t == 0) {
    float s = red[0] + red[1] + red[2] + red[3];
    float inv = 1.0f / fmaxf(sqrtf(s), EPSF);
    sinv = inv;
    invn[row] = inv;
    keys[row] = 0ull;           // any sim >= -1 encodes > 0
  }
  __syncthreads();
  float inv = sinv;
  ushort4 o4;
  o4.x = f2bf(v.x * inv);
  o4.y = f2bf(v.y * inv);
  o4.z = f2bf(v.z * inv);
  o4.w = f2bf(v.w * inv);
  ((ushort4*)(xb + (size_t)row * DIM))[t] = o4;
}

// ---------------- kernel 2: sim GEMM + argmax (256^2, 4-buf ring pipeline) ----------------
// 512 threads = 8 waves (2Mx4N), per-wave 128x64 output, BK=32.
// LDS: 4-buffer ring, A[4][256x32] + B[4][256x32] = 128 KiB (dynamic).
// Tile t: stage tile t+3 (4 gload_lds/thread); ds_read frags of buf[t&3];
// 32 MFMA; vmcnt(8) (t+1 landed, t+2/t+3 in flight); ONE barrier.
// Hazard: stage(t+3) writes buf[(t-1)&3]; all reads of it retired before the
// end-of-(t-1) barrier (reads precede MFMA precede barrier per wave).
__global__ __launch_bounds__(512, 2)
void k_sim(const unsigned short* __restrict__ xb, unsigned long long* __restrict__ keys) {
  extern __shared__ unsigned short lds_us[];   // A: [0,32768) ushorts, B: [32768,65536)

  int b = blockIdx.x;
  int bi = (int)((65.0f - sqrtf(4225.0f - 8.0f * (float)b)) * 0.5f);
  while ((bi + 1) * (65 - (bi + 1)) / 2 <= b) ++bi;
  while (bi * (65 - bi) / 2 > b) --bi;
  int bj = bi + (b - bi * (65 - bi) / 2);

  const int t = threadIdx.x, lane = t & 63, wv = t >> 6;
  const int wr = wv >> 2, wc = wv & 3;       // wave -> (2M x 4N) grid
  const int hi = lane >> 4, lo = lane & 15;
  const int rowBase = bi * 256, colBase = bj * 256;

  const unsigned short* gA = xb + (size_t)rowBase * DIM;
  const unsigned short* gB = xb + (size_t)colBase * DIM;

  // staging constants: chunk ci = j*512 + wv*64 + lane; row r=ci>>2, slot s=ci&3;
  // source chunk c = s ^ ((r>>1)&3)  -> lane-only: (lane&3)^((lane>>3)&3)
  const int sg = (lane & 3) ^ ((lane >> 3) & 3);
  const size_t soA0 = (size_t)(wv * 16 + (lane >> 2)) * DIM + sg * 8;   // j=0 rows 0..127
  const size_t soA1 = soA0 + (size_t)128 * DIM;                         // j=1 rows 128..255
  const int ldsA0 = wv * 512;          // uniform per wave (ushort offset)
  const int ldsA1 = 4096 + wv * 512;

#define STAGE_TILE(tt) do {                                                          \
    const size_t ko_ = (size_t)(tt) * 32;                                            \
    unsigned short* Ab_ = lds_us + ((tt) & 3) * 8192;                                \
    unsigned short* Bb_ = lds_us + 32768 + ((tt) & 3) * 8192;                        \
    __builtin_amdgcn_global_load_lds(                                                \
        (const __attribute__((address_space(1))) void*)(gA + soA0 + ko_),            \
        (__attribute__((address_space(3))) void*)(Ab_ + ldsA0), 16, 0, 0);           \
    __builtin_amdgcn_global_load_lds(                                                \
        (const __attribute__((address_space(1))) void*)(gA + soA1 + ko_),            \
        (__attribute__((address_space(3))) void*)(Ab_ + ldsA1), 16, 0, 0);           \
    __builtin_amdgcn_global_load_lds(                                                \
        (const __attribute__((address_space(1))) void*)(gB + soA0 + ko_),            \
        (__attribute__((address_space(3))) void*)(Bb_ + ldsA0), 16, 0, 0);           \
    __builtin_amdgcn_global_load_lds(                                                \
        (const __attribute__((address_space(1))) void*)(gB + soA1 + ko_),            \
        (__attribute__((address_space(3))) void*)(Bb_ + ldsA1), 16, 0, 0);           \
  } while (0)

  const f32x4 fzero = {0.f, 0.f, 0.f, 0.f};
  f32x4 acc[8][4];
#pragma unroll
  for (int i = 0; i < 8; ++i)
#pragma unroll
    for (int j = 0; j < 4; ++j) acc[i][j] = fzero;

  // fragment-read swizzled chunk: ch = hi ^ ((r>>1)&3) with r=16m+lo -> lane-only
  const int chux = (hi ^ ((lo >> 1) & 3)) * 8;

  // ---- prologue: stage tiles 0,1,2 ----
  STAGE_TILE(0);
  STAGE_TILE(1);
  STAGE_TILE(2);
  asm volatile("s_waitcnt vmcnt(8)" ::: "memory");   // tile 0 landed (own share)
  asm volatile("s_barrier" ::: "memory");            // block-wide

  for (int kt = 0; kt < NKT; ++kt) {
    if (kt < NKT - 3) STAGE_TILE(kt + 3);

    const unsigned short* Ab = lds_us + (kt & 3) * 8192;
    const unsigned short* Bb = lds_us + 32768 + (kt & 3) * 8192;
    s16x8 af[8], bfr[4];
#pragma unroll
    for (int mi = 0; mi < 8; ++mi) {
      int r = wr * 128 + mi * 16 + lo;
      af[mi] = *(const s16x8*)(Ab + r * 32 + chux);
    }
#pragma unroll
    for (int ni = 0; ni < 4; ++ni) {
      int r = wc * 64 + ni * 16 + lo;
      bfr[ni] = *(const s16x8*)(Bb + r * 32 + chux);
    }

    __builtin_amdgcn_s_setprio(1);
#pragma unroll
    for (int mi = 0; mi < 8; ++mi)
#pragma unroll
      for (int ni = 0; ni < 4; ++ni)
        acc[mi][ni] = __builtin_amdgcn_mfma_f32_16x16x32_bf16(af[mi], bfr[ni], acc[mi][ni], 0, 0, 0);
    __builtin_amdgcn_s_setprio(0);

    // counted drain: t+1's stages landed; t+2/t+3's 8 loads stay in flight
    if (kt < NKT - 3) asm volatile("s_waitcnt vmcnt(8)" ::: "memory");
    else              asm volatile("s_waitcnt vmcnt(0)" ::: "memory");
    asm volatile("s_barrier" ::: "memory");
  }
#undef STAGE_TILE

  // ---- per-row argmax (C layout: col=lane&15, row=(lane>>4)*4+reg) ----
#pragma unroll
  for (int am = 0; am < 8; ++am) {
#pragma unroll
    for (int reg = 0; reg < 4; ++reg) {
      int grow = rowBase + wr * 128 + am * 16 + hi * 4 + reg;
      float best = -10.0f;
      int bcol = 0;
#pragma unroll
      for (int ni = 0; ni < 4; ++ni) {
        int gcol = colBase + wc * 64 + ni * 16 + lo;
        float v = acc[am][ni][reg];
        v = (gcol == grow) ? -10.0f : v;   // mask diagonal
        if (v > best || (v == best && gcol < bcol)) { best = v; bcol = gcol; }
      }
#pragma unroll
      for (int m = 1; m < 16; m <<= 1) {
        float ov = __shfl_xor(best, m, 64);
        int oc = __shfl_xor(bcol, m, 64);
        if (ov > best || (ov == best && oc < bcol)) { best = ov; bcol = oc; }
      }
      if (lo == 0) {
        unsigned long long key = ((unsigned long long)encf(best) << 32) | (unsigned)(~bcol);
        atomicMax(&keys[grow], key);
      }
    }
  }

  // ---- per-col argmax (symmetric contribution), off-diagonal blocks only ----
  if (bi != bj) {
#pragma unroll
    for (int ni = 0; ni < 4; ++ni) {
      int gcol = colBase + wc * 64 + ni * 16 + lo;
      float best = -10.0f;
      int brow = 0;
#pragma unroll
      for (int am = 0; am < 8; ++am)
#pragma unroll
        for (int reg = 0; reg < 4; ++reg) {
          int grow = rowBase + wr * 128 + am * 16 + hi * 4 + reg;
          float v = acc[am][ni][reg];
          if (v > best || (v == best && grow < brow)) { best = v; brow = grow; }
        }
#pragma unroll
      for (int m = 16; m < 64; m <<= 1) {
        float ov = __shfl_xor(best, m, 64);
        int oc = __shfl_xor(brow, m, 64);
        if (ov > best || (ov == best && oc < brow)) { best = ov; brow = oc; }
      }
      if (hi == 0) {
        unsigned long long key = ((unsigned long long)encf(best) << 32) | (unsigned)(~brow);
        atomicMax(&keys[gcol], key);
      }
    }
  }
}

// ---------------- kernel 3: exact fp32 distance -> per-row partial ----------------
__global__ __launch_bounds__(256)
void k_dist(const float* __restrict__ x, const float* __restrict__ invn,
            const unsigned long long* __restrict__ keys, float* __restrict__ part) {
  int row = blockIdx.x, t = threadIdx.x;
  unsigned long long key = keys[row];
  int nb = (int)(~(unsigned)key);       // decode ~col
  float ia = invn[row], ib = invn[nb];
  float4 a = ((const float4*)(x + (size_t)row * DIM))[t];
  float4 b = ((const float4*)(x + (size_t)nb * DIM))[t];
  float d0 = a.x * ia - b.x * ib + EPSF;
  float d1 = a.y * ia - b.y * ib + EPSF;
  float d2 = a.z * ia - b.z * ib + EPSF;
  float d3 = a.w * ia - b.w * ib + EPSF;
  float ss = d0 * d0 + d1 * d1 + d2 * d2 + d3 * d3;
#pragma unroll
  for (int o = 32; o > 0; o >>= 1) ss += __shfl_down(ss, o, 64);
  __shared__ float red[4];
  if ((t & 63) == 0) red[t >> 6] = ss;
  __syncthreads();
  if (t == 0) {
    float s = red[0] + red[1] + red[2] + red[3];
    part[row] = logf(sqrtf(s) + EPSF);
  }
}

// ---------------- kernel 4: final reduce (no atomics) ----------------
__global__ __launch_bounds__(1024)
void k_final(const float* __restrict__ part, float* __restrict__ out) {
  int t = threadIdx.x;
  float s = 0.0f;
#pragma unroll
  for (int i = 0; i < N / 1024; ++i) s += part[t + i * 1024];
#pragma unroll
  for (int o = 32; o > 0; o >>= 1) s += __shfl_down(s, o, 64);
  __shared__ float red[16];
  if ((t & 63) == 0) red[t >> 6] = s;
  __syncthreads();
  if (t == 0) {
    float tot = 0.0f;
#pragma unroll
    for (int i = 0; i < 16; ++i) tot += red[i];
    out[0] = -tot / (float)N;
  }
}

extern "C" void kernel_launch(void* const* d_in, const int* in_sizes, int n_in,
                              void* d_out, int out_size, void* d_ws, size_t ws_size,
                              hipStream_t stream) {
  const float* x = (const float*)d_in[0];
  float* out = (float*)d_out;
  char* ws = (char*)d_ws;
  unsigned short* xb = (unsigned short*)(ws + XB_OFF);
  float* invn = (float*)(ws + INV_OFF);
  unsigned long long* keys = (unsigned long long*)(ws + KEY_OFF);
  float* part = (float*)(ws + PART_OFF);

  // allow 128 KiB dynamic LDS (idempotent; not a stream op, graph-capture-safe)
  (void)hipFuncSetAttribute((const void*)k_sim,
                            hipFuncAttributeMaxDynamicSharedMemorySize, 131072);

  k_norm<<<N, 256, 0, stream>>>(x, xb, invn, keys);
  k_sim<<<NTRI, 512, 131072, stream>>>(xb, keys);
  k_dist<<<N, 256, 0, stream>>>(x, invn, keys, part);
  k_final<<<1, 1024, 0, stream>>>(part, out);
}

// Round 9
// 229.250 us; speedup vs baseline: 1.2184x; 1.0464x over previous
//
#include <hip/hip_runtime.h>
#include <stdint.h>

#define N 8192
#define DIM 1024
#define EPSF 1e-8f
#define NBLK 32           // 8192/256
#define NTRI 528          // NBLK*(NBLK+1)/2
#define NKT 32            // K-tiles of 32: 1024/32

typedef __attribute__((ext_vector_type(4))) float f32x4;
typedef __attribute__((ext_vector_type(8))) short s16x8;

// ---- helpers ----
__device__ inline unsigned short f2bf(float f) {
  unsigned u = __float_as_uint(f);
  unsigned r = (u + 0x7FFFu + ((u >> 16) & 1u)) >> 16;
  return (unsigned short)r;
}

__device__ inline unsigned encf(float f) {
  unsigned u = __float_as_uint(f);
  return (u & 0x80000000u) ? ~u : (u | 0x80000000u);
}

// ws layout:
//   [0, 16MiB)       : xb   bf16 normalized rows, row-major 8192x1024 (ushort)
//   [16777216,+32KiB): invn fp32 per-row 1/max(norm,eps)
//   [16809984,+64KiB): keys u64 packed (enc(sim)<<32)|~col
//   [16875520,+32KiB): part fp32 per-row log(dist+eps)
#define XB_OFF   0
#define INV_OFF  16777216
#define KEY_OFF  16809984
#define PART_OFF 16875520

// ---------------- kernel 1: normalize + init ----------------
__global__ __launch_bounds__(256)
void k_norm(const float* __restrict__ x, unsigned short* __restrict__ xb,
            float* __restrict__ invn, unsigned long long* __restrict__ keys) {
  int row = blockIdx.x, t = threadIdx.x;
  const float4* xr = (const float4*)(x + (size_t)row * DIM);
  float4 v = xr[t];
  float ss = v.x * v.x + v.y * v.y + v.z * v.z + v.w * v.w;
#pragma unroll
  for (int o = 32; o > 0; o >>= 1) ss += __shfl_down(ss, o, 64);
  __shared__ float red[4];
  __shared__ float sinv;
  if ((t & 63) == 0) red[t >> 6] = ss;
  __syncthreads();
  if (t == 0) {
    float s = red[0] + red[1] + red[2] + red[3];
    float inv = 1.0f / fmaxf(sqrtf(s), EPSF);
    sinv = inv;
    invn[row] = inv;
    keys[row] = 0ull;           // any sim >= -1 encodes > 0
  }
  __syncthreads();
  float inv = sinv;
  ushort4 o4;
  o4.x = f2bf(v.x * inv);
  o4.y = f2bf(v.y * inv);
  o4.z = f2bf(v.z * inv);
  o4.w = f2bf(v.w * inv);
  ((ushort4*)(xb + (size_t)row * DIM))[t] = o4;
}

// ---------------- kernel 2: sim GEMM + argmax (256^2, 4-buf ring, CONST slots) ----------------
// 512 threads = 8 waves (2Mx4N), per-wave 128x64 output, BK=32.
// LDS ring: 4 slots A + 4 slots B = 128 KiB dynamic. K-loop unrolled x4 so every
// LDS offset is a COMPILE-TIME constant (lets llvm's waitcnt pass disambiguate
// ds_read slot t&3 from in-flight gload_lds writes to slot (t+3)&3 -> no
// conservative vmcnt(0) drain per tile).
// Tile t body: {12 ds_read (slot t&3); stage tile t+3 (slot (t+3)&3); 32 MFMA;
//               vmcnt(8); s_barrier}.
// Ledger: stage(t+3) overwrites slot(t-1), whose reads retired before the
// end-of-(t-1) barrier. End-of-t vmcnt(8) leaves exactly {t+2,t+3} (8 loads)
// in flight -> t+1's data proven landed before tile t+1 reads it.
__global__ __launch_bounds__(512, 2)
void k_sim(const unsigned short* __restrict__ xb, unsigned long long* __restrict__ keys) {
  extern __shared__ unsigned short lds_us[];   // A: [0,32768) ushorts, B: [32768,65536)

  int b = blockIdx.x;
  int bi = (int)((65.0f - sqrtf(4225.0f - 8.0f * (float)b)) * 0.5f);
  while ((bi + 1) * (65 - (bi + 1)) / 2 <= b) ++bi;
  while (bi * (65 - bi) / 2 > b) --bi;
  int bj = bi + (b - bi * (65 - bi) / 2);

  const int t = threadIdx.x, lane = t & 63, wv = t >> 6;
  const int wr = wv >> 2, wc = wv & 3;       // wave -> (2M x 4N) grid
  const int hi = lane >> 4, lo = lane & 15;
  const int rowBase = bi * 256, colBase = bj * 256;

  const unsigned short* gA = xb + (size_t)rowBase * DIM;
  const unsigned short* gB = xb + (size_t)colBase * DIM;

  // staging constants: chunk ci = j*512 + wv*64 + lane; row r=ci>>2, slot s=ci&3;
  // source chunk c = s ^ ((r>>1)&3)  -> lane-only: (lane&3)^((lane>>3)&3)
  const int sg = (lane & 3) ^ ((lane >> 3) & 3);
  const size_t soA0 = (size_t)(wv * 16 + (lane >> 2)) * DIM + sg * 8;   // j=0 rows 0..127
  const size_t soA1 = soA0 + (size_t)128 * DIM;                         // j=1 rows 128..255
  const int ldsA0 = wv * 512;          // uniform per wave (ushort offset)
  const int ldsA1 = 4096 + wv * 512;

// stage tile -> ring slot SLOT (compile-time const), k-offset KO (elements)
#define STAGE_SLOT(SLOT, KO) do {                                                    \
    const size_t ko_ = (size_t)(KO);                                                 \
    unsigned short* Ab_ = lds_us + (SLOT) * 8192;                                    \
    unsigned short* Bb_ = lds_us + 32768 + (SLOT) * 8192;                            \
    __builtin_amdgcn_global_load_lds(                                                \
        (const __attribute__((address_space(1))) void*)(gA + soA0 + ko_),            \
        (__attribute__((address_space(3))) void*)(Ab_ + ldsA0), 16, 0, 0);           \
    __builtin_amdgcn_global_load_lds(                                                \
        (const __attribute__((address_space(1))) void*)(gA + soA1 + ko_),            \
        (__attribute__((address_space(3))) void*)(Ab_ + ldsA1), 16, 0, 0);           \
    __builtin_amdgcn_global_load_lds(                                                \
        (const __attribute__((address_space(1))) void*)(gB + soA0 + ko_),            \
        (__attribute__((address_space(3))) void*)(Bb_ + ldsA0), 16, 0, 0);           \
    __builtin_amdgcn_global_load_lds(                                                \
        (const __attribute__((address_space(1))) void*)(gB + soA1 + ko_),            \
        (__attribute__((address_space(3))) void*)(Bb_ + ldsA1), 16, 0, 0);           \
  } while (0)

#define WB8 do { asm volatile("s_waitcnt vmcnt(8)" ::: "memory"); __builtin_amdgcn_s_barrier(); } while (0)
#define WB4 do { asm volatile("s_waitcnt vmcnt(4)" ::: "memory"); __builtin_amdgcn_s_barrier(); } while (0)
#define WB0 do { asm volatile("s_waitcnt vmcnt(0)" ::: "memory"); __builtin_amdgcn_s_barrier(); } while (0)

// tile body: reads (slot RS, const) -> stage -> MFMA -> wait+barrier
#define TILE(RS, STAGE_EXPR, WAIT_STMT) do {                                         \
    const unsigned short* Ab = lds_us + (RS) * 8192;                                 \
    const unsigned short* Bb = lds_us + 32768 + (RS) * 8192;                         \
    s16x8 af[8], bfr[4];                                                             \
    _Pragma("unroll")                                                                \
    for (int mi = 0; mi < 8; ++mi) {                                                 \
      int r = wr * 128 + mi * 16 + lo;                                               \
      af[mi] = *(const s16x8*)(Ab + r * 32 + chux);                                  \
    }                                                                                \
    _Pragma("unroll")                                                                \
    for (int ni = 0; ni < 4; ++ni) {                                                 \
      int r = wc * 64 + ni * 16 + lo;                                                \
      bfr[ni] = *(const s16x8*)(Bb + r * 32 + chux);                                 \
    }                                                                                \
    STAGE_EXPR;                                                                      \
    __builtin_amdgcn_s_setprio(1);                                                   \
    _Pragma("unroll")                                                                \
    for (int mi = 0; mi < 8; ++mi)                                                   \
      _Pragma("unroll")                                                              \
      for (int ni = 0; ni < 4; ++ni)                                                 \
        acc[mi][ni] = __builtin_amdgcn_mfma_f32_16x16x32_bf16(af[mi], bfr[ni],       \
                                                              acc[mi][ni], 0, 0, 0); \
    __builtin_amdgcn_s_setprio(0);                                                   \
    WAIT_STMT;                                                                       \
  } while (0)

  const f32x4 fzero = {0.f, 0.f, 0.f, 0.f};
  f32x4 acc[8][4];
#pragma unroll
  for (int i = 0; i < 8; ++i)
#pragma unroll
    for (int j = 0; j < 4; ++j) acc[i][j] = fzero;

  // fragment-read swizzled chunk: ch = hi ^ ((r>>1)&3) with r=16m+lo -> lane-only
  const int chux = (hi ^ ((lo >> 1) & 3)) * 8;

  // ---- prologue: stage tiles 0,1,2 (slots 0,1,2) ----
  STAGE_SLOT(0, 0);
  STAGE_SLOT(1, 32);
  STAGE_SLOT(2, 64);
  WB8;                                  // tile 0 landed (8 remain: tiles 1,2)

  // ---- main: tiles 0..27, all slots compile-time constants ----
  for (int kb = 0; kb < 28; kb += 4) {
    TILE(0, STAGE_SLOT(3, (kb + 3) * 32), WB8);
    TILE(1, STAGE_SLOT(0, (kb + 4) * 32), WB8);
    TILE(2, STAGE_SLOT(1, (kb + 5) * 32), WB8);
    TILE(3, STAGE_SLOT(2, (kb + 6) * 32), WB8);
  }
  // ---- tail: tiles 28..31 ----
  TILE(0, STAGE_SLOT(3, 31 * 32), WB8);   // tile 28, stages tile 31
  TILE(1, (void)0, WB4);                  // tile 29 (tile 30 proven)
  TILE(2, (void)0, WB0);                  // tile 30 (tile 31 proven)
  TILE(3, (void)0, (void)0);              // tile 31, no wait needed

#undef TILE
#undef STAGE_SLOT
#undef WB8
#undef WB4
#undef WB0

  // ---- per-row argmax (C layout: col=lane&15, row=(lane>>4)*4+reg) ----
#pragma unroll
  for (int am = 0; am < 8; ++am) {
#pragma unroll
    for (int reg = 0; reg < 4; ++reg) {
      int grow = rowBase + wr * 128 + am * 16 + hi * 4 + reg;
      float best = -10.0f;
      int bcol = 0;
#pragma unroll
      for (int ni = 0; ni < 4; ++ni) {
        int gcol = colBase + wc * 64 + ni * 16 + lo;
        float v = acc[am][ni][reg];
        v = (gcol == grow) ? -10.0f : v;   // mask diagonal
        if (v > best || (v == best && gcol < bcol)) { best = v; bcol = gcol; }
      }
#pragma unroll
      for (int m = 1; m < 16; m <<= 1) {
        float ov = __shfl_xor(best, m, 64);
        int oc = __shfl_xor(bcol, m, 64);
        if (ov > best || (ov == best && oc < bcol)) { best = ov; bcol = oc; }
      }
      if (lo == 0) {
        unsigned long long key = ((unsigned long long)encf(best) << 32) | (unsigned)(~bcol);
        atomicMax(&keys[grow], key);
      }
    }
  }

  // ---- per-col argmax (symmetric contribution), off-diagonal blocks only ----
  if (bi != bj) {
#pragma unroll
    for (int ni = 0; ni < 4; ++ni) {
      int gcol = colBase + wc * 64 + ni * 16 + lo;
      float best = -10.0f;
      int brow = 0;
#pragma unroll
      for (int am = 0; am < 8; ++am)
#pragma unroll
        for (int reg = 0; reg < 4; ++reg) {
          int grow = rowBase + wr * 128 + am * 16 + hi * 4 + reg;
          float v = acc[am][ni][reg];
          if (v > best || (v == best && grow < brow)) { best = v; brow = grow; }
        }
#pragma unroll
      for (int m = 16; m < 64; m <<= 1) {
        float ov = __shfl_xor(best, m, 64);
        int oc = __shfl_xor(brow, m, 64);
        if (ov > best || (ov == best && oc < brow)) { best = ov; brow = oc; }
      }
      if (hi == 0) {
        unsigned long long key = ((unsigned long long)encf(best) << 32) | (unsigned)(~brow);
        atomicMax(&keys[gcol], key);
      }
    }
  }
}

// ---------------- kernel 3: exact fp32 distance -> per-row partial ----------------
__global__ __launch_bounds__(256)
void k_dist(const float* __restrict__ x, const float* __restrict__ invn,
            const unsigned long long* __restrict__ keys, float* __restrict__ part) {
  int row = blockIdx.x, t = threadIdx.x;
  unsigned long long key = keys[row];
  int nb = (int)(~(unsigned)key);       // decode ~col
  float ia = invn[row], ib = invn[nb];
  float4 a = ((const float4*)(x + (size_t)row * DIM))[t];
  float4 b = ((const float4*)(x + (size_t)nb * DIM))[t];
  float d0 = a.x * ia - b.x * ib + EPSF;
  float d1 = a.y * ia - b.y * ib + EPSF;
  float d2 = a.z * ia - b.z * ib + EPSF;
  float d3 = a.w * ia - b.w * ib + EPSF;
  float ss = d0 * d0 + d1 * d1 + d2 * d2 + d3 * d3;
#pragma unroll
  for (int o = 32; o > 0; o >>= 1) ss += __shfl_down(ss, o, 64);
  __shared__ float red[4];
  if ((t & 63) == 0) red[t >> 6] = ss;
  __syncthreads();
  if (t == 0) {
    float s = red[0] + red[1] + red[2] + red[3];
    part[row] = logf(sqrtf(s) + EPSF);
  }
}

// ---------------- kernel 4: final reduce (no atomics) ----------------
__global__ __launch_bounds__(1024)
void k_final(const float* __restrict__ part, float* __restrict__ out) {
  int t = threadIdx.x;
  float s = 0.0f;
#pragma unroll
  for (int i = 0; i < N / 1024; ++i) s += part[t + i * 1024];
#pragma unroll
  for (int o = 32; o > 0; o >>= 1) s += __shfl_down(s, o, 64);
  __shared__ float red[16];
  if ((t & 63) == 0) red[t >> 6] = s;
  __syncthreads();
  if (t == 0) {
    float tot = 0.0f;
#pragma unroll
    for (int i = 0; i < 16; ++i) tot += red[i];
    out[0] = -tot / (float)N;
  }
}

extern "C" void kernel_launch(void* const* d_in, const int* in_sizes, int n_in,
                              void* d_out, int out_size, void* d_ws, size_t ws_size,
                              hipStream_t stream) {
  const float* x = (const float*)d_in[0];
  float* out = (float*)d_out;
  char* ws = (char*)d_ws;
  unsigned short* xb = (unsigned short*)(ws + XB_OFF);
  float* invn = (float*)(ws + INV_OFF);
  unsigned long long* keys = (unsigned long long*)(ws + KEY_OFF);
  float* part = (float*)(ws + PART_OFF);

  // allow 128 KiB dynamic LDS (idempotent; not a stream op, graph-capture-safe)
  (void)hipFuncSetAttribute((const void*)k_sim,
                            hipFuncAttributeMaxDynamicSharedMemorySize, 131072);

  k_norm<<<N, 256, 0, stream>>>(x, xb, invn, keys);
  k_sim<<<NTRI, 512, 131072, stream>>>(xb, keys);
  k_dist<<<N, 256, 0, stream>>>(x, invn, keys, part);
  k_final<<<1, 1024, 0, stream>>>(part, out);
}